// Round 1
// baseline (2965.129 us; speedup 1.0000x reference)
//
#include <hip/hip_runtime.h>

typedef unsigned short ushort_t;
typedef __attribute__((ext_vector_type(8))) short short8;
typedef __attribute__((ext_vector_type(4))) float floatx4;

#define B_ 256
#define T_ 128
#define E_ 300
#define H_ 512
#define NE_ 127   // T-1 reduce events
#define NT_ 255   // 2T-1 transitions

__device__ inline ushort_t f2bf(float f){
  unsigned u = __builtin_bit_cast(unsigned, f);
  unsigned r = u + 0x7FFFu + ((u >> 16) & 1u);
  return (ushort_t)(r >> 16);
}
__device__ inline float bf2f(ushort_t h){
  unsigned u = ((unsigned)h) << 16;
  return __builtin_bit_cast(float, u);
}
__device__ inline float sigm(float x){ return 1.0f / (1.0f + __expf(-x)); }

// ---------------------------------------------------------------------------
// Pack a KxN row-major fp32 weight into MFMA B-fragment order (bf16):
// dst[((ct*NS + s)*64 + lane)*8 + j] = W[32*s + 8*(lane>>4) + j][16*ct + (lane&15)]
// so the GEMM loads one coalesced dwordx4 per lane per (col-tile, k-slab).
// ---------------------------------------------------------------------------
__global__ __launch_bounds__(256) void pack_w_kernel(const float* __restrict__ W,
    ushort_t* __restrict__ dst, int K, int N, int NS, int total){
  int t = blockIdx.x * 256 + threadIdx.x;
  if (t >= total) return;
  int L = t & 63;
  int s = (t >> 6) % NS;
  int ct = t / (64 * NS);
  int n = ct * 16 + (L & 15);
  int kbase = s * 32 + ((L >> 4) << 3);
  short8 pack;
  #pragma unroll
  for (int j = 0; j < 8; ++j){
    int k = kbase + j;
    pack[j] = (k < K) ? (short)f2bf(W[(size_t)k * N + n]) : (short)0;
  }
  *(short8*)(dst + (size_t)t * 8) = pack;
}

// ---------------------------------------------------------------------------
// Stack-machine simulation (indices only). Values: -1 = zeros, 0..T-1 = leaf
// token t, T+e = output of reduce event e. Emits per-event child indices and
// the per-batch root index.
// ---------------------------------------------------------------------------
__global__ void sched_kernel(const int* __restrict__ trans, int* __restrict__ sl,
    int* __restrict__ sr, int* __restrict__ root){
  __shared__ int stk[32 * 128];
  __shared__ int trs[NT_ * 32];
  int tid = threadIdx.x;          // 0..31
  int b0 = blockIdx.x * 32;
  for (int i = tid; i < NT_ * 32; i += 32){
    int t = i >> 5, bb = i & 31;
    trs[i] = trans[t * B_ + b0 + bb];
  }
  for (int i = 0; i < 128; ++i) stk[tid * 128 + i] = -1;
  __syncthreads();
  int b = b0 + tid;
  int sp = 0, bp = T_, e = 0;
  for (int t = 0; t < NT_; ++t){
    int tr = trs[t * 32 + tid];
    if (tr == 0){
      int pos = sp; if (pos > 127) pos = 127; if (pos < 0) pos = 0;
      stk[tid * 128 + pos] = bp - 1;
      sp += 1; bp -= 1;
    } else {
      int i2 = sp - 2; if (i2 < 0) i2 = 0; if (i2 > 127) i2 = 127;
      int i1 = sp - 1; if (i1 < 0) i1 = 0; if (i1 > 127) i1 = 127;
      int l = stk[tid * 128 + i2];
      int r = stk[tid * 128 + i1];
      if (e < NE_){ sl[e * B_ + b] = l; sr[e * B_ + b] = r; }
      int pos = sp - 2; if (pos < 0) pos = 0; if (pos > 127) pos = 127;
      stk[tid * 128 + pos] = (e < NE_) ? (T_ + e) : -1;
      e += 1; sp -= 1;
    }
  }
  for (int k = e; k < NE_; ++k){ sl[k * B_ + b] = -1; sr[k * B_ + b] = -1; }
  int ip = sp - 1; if (ip < 0) ip = 0; if (ip > 127) ip = 127;
  root[b] = stk[tid * 128 + ip];
}

// ---------------------------------------------------------------------------
// Leaf phase: c = x@W_proj + b_proj ; h = sigmoid(x@W_gate + b_gate)*tanh(c)
// Fused dual-GEMM, MFMA 16x16x32 bf16, fp32 accumulate. M=32768, K=300(pad
// 320), N=512. WG = 4 waves x 16 rows = 64 rows, 64 cols (both weights).
// ---------------------------------------------------------------------------
__global__ __launch_bounds__(256) void leaf_kernel(const float* __restrict__ x,
    const ushort_t* __restrict__ WpP, const ushort_t* __restrict__ WgP,
    const float* __restrict__ b_proj, const float* __restrict__ b_gate,
    ushort_t* __restrict__ leaf_h, ushort_t* __restrict__ leaf_c){
  int wave = threadIdx.x >> 6, lane = threadIdx.x & 63;
  int r0 = blockIdx.x * 64 + wave * 16;
  int c0 = blockIdx.y * 4;          // base 16-col tile
  int arow = r0 + (lane & 15);
  int klane = (lane >> 4) << 3;
  const float* xrow = x + (size_t)arow * E_;
  floatx4 accP[4], accG[4];
  #pragma unroll
  for (int i = 0; i < 4; ++i){ accP[i] = (floatx4){0,0,0,0}; accG[i] = (floatx4){0,0,0,0}; }
  #pragma unroll
  for (int s = 0; s < 10; ++s){
    int k0 = s * 32 + klane;
    float xv[8];
    if (k0 + 7 < E_){
      float4 v0 = *(const float4*)(xrow + k0);
      float4 v1 = *(const float4*)(xrow + k0 + 4);
      xv[0]=v0.x; xv[1]=v0.y; xv[2]=v0.z; xv[3]=v0.w;
      xv[4]=v1.x; xv[5]=v1.y; xv[6]=v1.z; xv[7]=v1.w;
    } else {
      #pragma unroll
      for (int j = 0; j < 8; ++j) xv[j] = (k0 + j < E_) ? xrow[k0 + j] : 0.0f;
    }
    short8 a;
    #pragma unroll
    for (int j = 0; j < 8; ++j) a[j] = (short)f2bf(xv[j]);
    #pragma unroll
    for (int cc = 0; cc < 4; ++cc){
      short8 bp = *(const short8*)(WpP + (((size_t)(c0 + cc) * 10 + s) * 64 + lane) * 8);
      accP[cc] = __builtin_amdgcn_mfma_f32_16x16x32_bf16(a, bp, accP[cc], 0, 0, 0);
      short8 bg = *(const short8*)(WgP + (((size_t)(c0 + cc) * 10 + s) * 64 + lane) * 8);
      accG[cc] = __builtin_amdgcn_mfma_f32_16x16x32_bf16(a, bg, accG[cc], 0, 0, 0);
    }
  }
  int rbase = r0 + ((lane >> 4) << 2);
  #pragma unroll
  for (int cc = 0; cc < 4; ++cc){
    int col = (c0 + cc) * 16 + (lane & 15);
    float bp = b_proj[col], bg = b_gate[col];
    #pragma unroll
    for (int r = 0; r < 4; ++r){
      int row = rbase + r;
      float cv = accP[cc][r] + bp;
      float hv = sigm(accG[cc][r] + bg) * tanhf(cv);
      size_t o = (size_t)row * H_ + col;
      leaf_c[o] = f2bf(cv);
      leaf_h[o] = f2bf(hv);
    }
  }
}

// ---------------------------------------------------------------------------
// One reduce event: proj = [h_l | h_r] @ W_reduce + b_reduce, LSTM cell.
// Grid (4,32): blockIdx.x = 64-row tile, blockIdx.y = 16-col group; each WG
// computes its 16 cols for ALL 5 gates so the epilogue is local.
// Wave = 16 rows x (5x16) cols, K=1024 unrolled: 160 MFMAs/wave.
// ---------------------------------------------------------------------------
__global__ __launch_bounds__(256) void event_kernel(int k,
    const ushort_t* __restrict__ WrP, const float* __restrict__ b_reduce,
    const ushort_t* __restrict__ leaf_h, const ushort_t* __restrict__ leaf_c,
    ushort_t* __restrict__ node_h, float* __restrict__ node_c,
    const int* __restrict__ sl, const int* __restrict__ sr,
    const int* __restrict__ root, float* __restrict__ out){
  int wave = threadIdx.x >> 6, lane = threadIdx.x & 63;
  int r0 = blockIdx.x * 64 + wave * 16;
  int c = blockIdx.y;
  int aRow = r0 + (lane & 15);
  int klane = (lane >> 4) << 3;
  int li = sl[k * B_ + aRow];
  int ri = sr[k * B_ + aRow];
  const ushort_t* pL = (li < 0) ? (const ushort_t*)0 :
      (li < T_ ? leaf_h + ((size_t)aRow * T_ + li) * H_
               : node_h + ((size_t)aRow * NE_ + (li - T_)) * H_);
  const ushort_t* pR = (ri < 0) ? (const ushort_t*)0 :
      (ri < T_ ? leaf_h + ((size_t)aRow * T_ + ri) * H_
               : node_h + ((size_t)aRow * NE_ + (ri - T_)) * H_);
  floatx4 acc[5];
  #pragma unroll
  for (int g = 0; g < 5; ++g) acc[g] = (floatx4){0,0,0,0};
  #pragma unroll
  for (int s = 0; s < 32; ++s){
    const ushort_t* p = (s < 16) ? pL : pR;
    int koff = (s & 15) * 32 + klane;
    short8 a = {0,0,0,0,0,0,0,0};
    if (p) a = *(const short8*)(p + koff);
    #pragma unroll
    for (int g = 0; g < 5; ++g){
      int cB = g * 32 + c;
      short8 bf = *(const short8*)(WrP + (((size_t)cB * 32 + s) * 64 + lane) * 8);
      acc[g] = __builtin_amdgcn_mfma_f32_16x16x32_bf16(a, bf, acc[g], 0, 0, 0);
    }
  }
  int colh = c * 16 + (lane & 15);
  float bias[5];
  #pragma unroll
  for (int g = 0; g < 5; ++g) bias[g] = b_reduce[g * H_ + colh];
  int rbase = r0 + ((lane >> 4) << 2);
  #pragma unroll
  for (int r = 0; r < 4; ++r){
    int bb = rbase + r;
    int l2 = sl[k * B_ + bb], r2 = sr[k * B_ + bb];
    float cl = (l2 < 0) ? 0.0f : (l2 < T_ ? bf2f(leaf_c[((size_t)bb * T_ + l2) * H_ + colh])
                                          : node_c[((size_t)bb * NE_ + (l2 - T_)) * H_ + colh]);
    float cr = (r2 < 0) ? 0.0f : (r2 < T_ ? bf2f(leaf_c[((size_t)bb * T_ + r2) * H_ + colh])
                                          : node_c[((size_t)bb * NE_ + (r2 - T_)) * H_ + colh]);
    float pi  = acc[0][r] + bias[0];
    float pfl = acc[1][r] + bias[1];
    float pfr = acc[2][r] + bias[2];
    float pg  = acc[3][r] + bias[3];
    float po  = acc[4][r] + bias[4];
    float cn = sigm(pfl) * cl + sigm(pfr) * cr + sigm(pi) * tanhf(pg);
    float hn = sigm(po) * tanhf(cn);
    size_t o = ((size_t)bb * NE_ + k) * H_ + colh;
    node_c[o] = cn;
    node_h[o] = f2bf(hn);
    if (root[bb] == T_ + k) out[(size_t)bb * H_ + colh] = hn;  // fp32 root h
  }
}

// Root-is-a-leaf fallback (not hit for T=128 valid parses, but d_out is
// poisoned so every row must be covered in all cases).
__global__ __launch_bounds__(256) void fixup_kernel(const int* __restrict__ root,
    const ushort_t* __restrict__ leaf_h, float* __restrict__ out){
  int i = blockIdx.x * 256 + threadIdx.x;
  if (i >= B_ * H_) return;
  int b = i >> 9, j = i & (H_ - 1);
  int rt = root[b];
  if (rt >= 0 && rt < T_) out[i] = bf2f(leaf_h[((size_t)b * T_ + rt) * H_ + j]);
  else if (rt < 0) out[i] = 0.0f;
}

extern "C" void kernel_launch(void* const* d_in, const int* in_sizes, int n_in,
                              void* d_out, int out_size, void* d_ws, size_t ws_size,
                              hipStream_t stream){
  const float* x        = (const float*)d_in[0];
  const float* W_proj   = (const float*)d_in[1];
  const float* b_proj   = (const float*)d_in[2];
  const float* W_gate   = (const float*)d_in[3];
  const float* b_gate   = (const float*)d_in[4];
  const float* W_reduce = (const float*)d_in[5];
  const float* b_reduce = (const float*)d_in[6];
  const int*   trans    = (const int*)d_in[7];
  float* out = (float*)d_out;

  char* ws = (char*)d_ws;
  size_t o = 0;
  ushort_t* WpP    = (ushort_t*)(ws + o); o += (size_t)32*10*64*8*2;   // 320 KB
  ushort_t* WgP    = (ushort_t*)(ws + o); o += (size_t)32*10*64*8*2;
  ushort_t* WrP    = (ushort_t*)(ws + o); o += (size_t)160*32*64*8*2;  // 5 MB
  ushort_t* leaf_h = (ushort_t*)(ws + o); o += (size_t)B_*T_*H_*2;     // 32 MB
  ushort_t* leaf_c = (ushort_t*)(ws + o); o += (size_t)B_*T_*H_*2;     // 32 MB
  ushort_t* node_h = (ushort_t*)(ws + o); o += (size_t)B_*NE_*H_*2;    // 31.75 MB
  float*    node_c = (float*)(ws + o);    o += (size_t)B_*NE_*H_*4;    // 63.5 MB
  int* sl   = (int*)(ws + o); o += (size_t)NE_*B_*4;
  int* sr   = (int*)(ws + o); o += (size_t)NE_*B_*4;
  int* root = (int*)(ws + o); o += (size_t)B_*4;
  (void)ws_size; (void)in_sizes; (void)n_in; (void)out_size;

  pack_w_kernel<<<(32*10*64 + 255)/256, 256, 0, stream>>>(W_proj, WpP, 300, 512, 10, 32*10*64);
  pack_w_kernel<<<(32*10*64 + 255)/256, 256, 0, stream>>>(W_gate, WgP, 300, 512, 10, 32*10*64);
  pack_w_kernel<<<(160*32*64 + 255)/256, 256, 0, stream>>>(W_reduce, WrP, 1024, 2560, 32, 160*32*64);
  sched_kernel<<<8, 32, 0, stream>>>(trans, sl, sr, root);
  leaf_kernel<<<dim3(512, 8), 256, 0, stream>>>(x, WpP, WgP, b_proj, b_gate, leaf_h, leaf_c);
  for (int k = 0; k < NE_; ++k){
    event_kernel<<<dim3(4, 32), 256, 0, stream>>>(k, WrP, b_reduce, leaf_h, leaf_c,
                                                  node_h, node_c, sl, sr, root, out);
  }
  fixup_kernel<<<(B_*H_ + 255)/256, 256, 0, stream>>>(root, leaf_h, out);
}